// Round 7
// baseline (48.333 us; speedup 1.0000x reference)
//
#include <hip/hip_runtime.h>
#include <stdint.h>

#define NB 2048
#define NCLASSES 80
#define CONF_T 0.05f
#define IOU_T 0.5f
#define MAX_DET 100
#define MAX_PER_CLASS 100

typedef unsigned long long u64;
typedef unsigned int u32;

__device__ __forceinline__ u64 shfl_xor_u64(u64 v, int mask) {
    int lo = (int)(u32)v, hi = (int)(u32)(v >> 32);
    lo = __shfl_xor(lo, mask, 64);
    hi = __shfl_xor(hi, mask, 64);
    return ((u64)(u32)hi << 32) | (u32)lo;
}

// ====================================================================
// K_nms: one wave per (class, batch). Self-buckets class c by scanning
// pred (no dependency on any other kernel), in-wave descending sort
// (unique keys => exact global tie-break), in-register greedy NMS,
// suppressed orig-indices -> global bitmap via atomicOr (set semantics
// => append order irrelevant => deterministic). Exact cnt>64 fallback.
// ====================================================================
__global__ __launch_bounds__(64) void k_nms(const float* __restrict__ pred,
                                            u32* __restrict__ supMaskG) {
    const int c = blockIdx.x, b = blockIdx.y, lane = threadIdx.x;
    __shared__ u64 list[NB];              // 16 KB (worst case whole batch one class)
    __shared__ unsigned char fstate[NB];  // fallback only
    const float* P = pred + (size_t)b * NB * 6;

    // ---- bucket: scan cls/score pairs, ballot-compact into LDS ----
    int cnt = 0;
    for (int base = 0; base < NB; base += 64) {
        int i = base + lane;
        float2 cs = *reinterpret_cast<const float2*>(P + i * 6 + 4); // (cls, score), 8B-aligned
        bool v = (cs.y > CONF_T) && ((int)cs.x == c);
        u64 m = __ballot(v);
        if (v) {
            int pos = cnt + __popcll(m & ((1ull << lane) - 1ull));
            list[pos] = ((u64)__float_as_uint(cs.y) << 32) | (u32)i;
        }
        cnt += __popcll(m);
    }
    __syncthreads();
    if (cnt < 2) return;

    if (cnt <= 64) {
        // ---- in-wave descending bitonic sort (validated network) ----
        u64 v = (lane < cnt) ? list[lane] : 0ull;
        for (int k = 2; k <= 64; k <<= 1)
            for (int j = k >> 1; j >= 1; j >>= 1) {
                u64 p = shfl_xor_u64(v, j);
                bool low = (lane & j) == 0, up = (lane & k) == 0;
                v = (low == up) ? (v > p ? v : p) : (v < p ? v : p);
            }
        int orig = (int)(u32)v;
        float x1 = 0.f, y1 = 0.f, x2 = 0.f, y2 = 0.f, ar = 0.f;
        if (lane < cnt) {
            const float* q = P + orig * 6;
            x1 = q[0]; y1 = q[1]; x2 = q[2]; y2 = q[3];
            ar = fmaxf(x2 - x1, 0.f) * fmaxf(y2 - y1, 0.f);
        }
        u64 aliveM = __ballot(lane < cnt);
        for (int a = 0; a + 1 < cnt; ++a) {
            if (!((aliveM >> a) & 1ull)) continue;   // uniform
            float ax1 = __shfl(x1, a, 64), ay1 = __shfl(y1, a, 64);
            float ax2 = __shfl(x2, a, 64), ay2 = __shfl(y2, a, 64);
            float aar = __shfl(ar, a, 64);
            bool kill = false;
            if (lane > a && ((aliveM >> lane) & 1ull)) {
                float ix1 = fmaxf(ax1, x1), iy1 = fmaxf(ay1, y1);
                float ix2 = fminf(ax2, x2), iy2 = fminf(ay2, y2);
                float inter = fmaxf(ix2 - ix1, 0.f) * fmaxf(iy2 - iy1, 0.f);
                float uni = aar + ar - inter;
                kill = inter / fmaxf(uni, 1e-8f) > IOU_T;
            }
            aliveM &= ~__ballot(kill);
        }
        if (lane < cnt && !((aliveM >> lane) & 1ull))
            atomicOr(&supMaskG[b * 64 + (orig >> 5)], 1u << (orig & 31));
    } else {
        // ---- exact slow fallback (statistically never taken) ----
        for (int e = lane; e < cnt; e += 64) fstate[e] = 0;
        __syncthreads();
        int keptCount = 0;
        for (;;) {
            u64 best = 0ull; int bi = -1;
            for (int e = lane; e < cnt; e += 64)
                if (fstate[e] == 0) { u64 kv = list[e]; if (kv > best) { best = kv; bi = e; } }
            for (int d = 32; d >= 1; d >>= 1) {
                u64 ob = shfl_xor_u64(best, d);
                int obi = __shfl_xor(bi, d, 64);
                if (ob > best) { best = ob; bi = obi; }
            }
            if (best == 0ull) break;
            keptCount++;
            int orig = (int)(u32)best;
            const float* q = P + orig * 6;
            float ax1 = q[0], ay1 = q[1], ax2 = q[2], ay2 = q[3];
            float aar = fmaxf(ax2 - ax1, 0.f) * fmaxf(ay2 - ay1, 0.f);
            if (lane == 0) fstate[bi] = 1;
            __syncthreads();
            for (int e = lane; e < cnt; e += 64) {
                if (fstate[e] == 0) {
                    u64 kv = list[e];
                    int o2 = (int)(u32)kv;
                    const float* q2 = P + o2 * 6;
                    float bx1 = q2[0], by1 = q2[1], bx2 = q2[2], by2 = q2[3];
                    float br = fmaxf(bx2 - bx1, 0.f) * fmaxf(by2 - by1, 0.f);
                    float ix1 = fmaxf(ax1, bx1), iy1 = fmaxf(ay1, by1);
                    float ix2 = fminf(ax2, bx2), iy2 = fminf(ay2, by2);
                    float inter = fmaxf(ix2 - ix1, 0.f) * fmaxf(iy2 - iy1, 0.f);
                    if (inter / fmaxf(aar + br - inter, 1e-8f) > IOU_T) {
                        fstate[e] = 2;
                        atomicOr(&supMaskG[b * 64 + (o2 >> 5)], 1u << (o2 & 31));
                    }
                }
            }
            if (keptCount > MAX_PER_CLASS && lane == 0)   // cap: NMS-kept, output-dropped
                atomicOr(&supMaskG[b * 64 + (orig >> 5)], 1u << (orig & 31));
            __syncthreads();
        }
    }
}

// ====================================================================
// K_out: per batch, 256 thr. Hybrid bitonic sort with 8 elems/thread
// (wave owns a 512-elem segment; register-resident through k=512;
// reg-local pairs for j in {64,128,256}, shfl for j<=32; only j>=512
// via LDS => 6 sort barriers at 4 waves). Then bitmap check + ballot
// compaction + output (validated round-6 k3 logic).
// ====================================================================
__global__ __launch_bounds__(256) void k_out(const float* __restrict__ pred,
                                             const u32* __restrict__ supMaskG,
                                             float* __restrict__ out, int B) {
    const int b = blockIdx.x, tid = threadIdx.x;
    const int lane = tid & 63, wave = tid >> 6;          // 4 waves
    __shared__ u64 keys[NB];                             // 16 KB
    __shared__ u32 sm[64];
    __shared__ u64 keptM[32];
    __shared__ int kcnt[32], kbase[32];
    const float* P = pred + (size_t)b * NB * 6;

    const int sbase = wave * 512;
    u64 K[8];
    #pragma unroll
    for (int t = 0; t < 8; ++t) {
        int i = sbase + lane + 64 * t;
        float s = P[i * 6 + 5];
        K[t] = (s > CONF_T) ? (((u64)__float_as_uint(s) << 32) | (u32)i)
                            : (u64)(u32)i;
    }

    auto locp = [&](u64& X, u64& Y, int ixlow, int k) {  // X at lower index
        bool up = ((ixlow & k) == 0);
        u64 mx = X > Y ? X : Y, mn = X > Y ? Y : X;
        X = up ? mx : mn; Y = up ? mn : mx;
    };
    auto shf = [&](u64& V, int iv, int j, int k) {
        u64 p = shfl_xor_u64(V, j);
        bool low = ((lane & j) == 0);
        bool up  = ((iv & k) == 0);
        V = (low == up) ? (V > p ? V : p) : (V < p ? V : p);
    };
    auto tail = [&](int k, int jstart) {
        if (jstart >= 256) {
            locp(K[0], K[4], sbase + lane +   0, k);
            locp(K[1], K[5], sbase + lane +  64, k);
            locp(K[2], K[6], sbase + lane + 128, k);
            locp(K[3], K[7], sbase + lane + 192, k);
        }
        if (jstart >= 128) {
            locp(K[0], K[2], sbase + lane +   0, k);
            locp(K[1], K[3], sbase + lane +  64, k);
            locp(K[4], K[6], sbase + lane + 256, k);
            locp(K[5], K[7], sbase + lane + 320, k);
        }
        if (jstart >= 64) {
            locp(K[0], K[1], sbase + lane +   0, k);
            locp(K[2], K[3], sbase + lane + 128, k);
            locp(K[4], K[5], sbase + lane + 256, k);
            locp(K[6], K[7], sbase + lane + 384, k);
        }
        for (int j = (jstart > 32 ? 32 : jstart); j >= 1; j >>= 1) {
            #pragma unroll
            for (int t = 0; t < 8; ++t) shf(K[t], sbase + lane + 64 * t, j, k);
        }
    };
    auto store = [&]() {
        #pragma unroll
        for (int t = 0; t < 8; ++t) keys[sbase + lane + 64 * t] = K[t];
    };
    auto load = [&]() {
        #pragma unroll
        for (int t = 0; t < 8; ++t) K[t] = keys[sbase + lane + 64 * t];
    };
    auto ldsPhase = [&](int j, int k) {
        for (int pp = tid; pp < (NB >> 1); pp += 256) {
            int i1 = ((pp & ~(j - 1)) << 1) | (pp & (j - 1));
            int i2 = i1 + j;
            bool up = ((i1 & k) == 0);
            u64 a = keys[i1], c = keys[i2];
            if (up ? (a < c) : (a > c)) { keys[i1] = c; keys[i2] = a; }
        }
    };

    // k = 2..512: fully register-resident within each wave's segment.
    for (int k = 2; k <= 512; k <<= 1) tail(k, k >> 1);
    store();
    __syncthreads();

    // k = 1024
    ldsPhase(512, 1024);  __syncthreads();
    load(); tail(1024, 256); store(); __syncthreads();

    // k = 2048
    ldsPhase(1024, 2048); __syncthreads();
    ldsPhase(512, 2048);  __syncthreads();
    load(); tail(2048, 256); store();
    if (tid < 64) sm[tid] = supMaskG[b * 64 + tid];
    __syncthreads();

    // ---- compaction over sorted keys ----
    for (int cc = wave; cc < 32; cc += 4) {
        u64 k = keys[cc * 64 + lane];
        int orig = (int)(u32)k;
        bool kp = ((k >> 32) != 0) && !((sm[orig >> 5] >> (orig & 31)) & 1u);
        u64 m = __ballot(kp);
        if (lane == 0) { keptM[cc] = m; kcnt[cc] = __popcll(m); }
    }
    __syncthreads();
    if (tid < 32) {
        int s = 0;
        for (int c2 = 0; c2 < tid; ++c2) s += kcnt[c2];
        kbase[tid] = s;
    }
    __syncthreads();

    float* boxes_out   = out + (size_t)b * MAX_DET * 4;
    float* scores_out  = out + (size_t)B * MAX_DET * 4 + (size_t)b * MAX_DET;
    float* classes_out = out + (size_t)B * MAX_DET * 5 + (size_t)b * MAX_DET;
    float* numdet_out  = out + (size_t)B * MAX_DET * 6 + b;

    for (int cc = wave; cc < 32; cc += 4) {
        u64 m = keptM[cc];
        bool kp = (m >> lane) & 1ull;
        int pos = kbase[cc] + __popcll(m & ((1ull << lane) - 1ull));
        if (kp && pos < MAX_DET) {
            u64 k = keys[cc * 64 + lane];
            int orig = (int)(u32)k;
            const float* q = P + orig * 6;
            boxes_out[pos * 4 + 0] = q[0];
            boxes_out[pos * 4 + 1] = q[1];
            boxes_out[pos * 4 + 2] = q[2];
            boxes_out[pos * 4 + 3] = q[3];
            scores_out[pos]  = __uint_as_float((u32)(k >> 32));
            classes_out[pos] = q[4];
        }
    }
    int total = kbase[31] + kcnt[31];
    int nd = total < MAX_DET ? total : MAX_DET;
    for (int p = nd + tid; p < MAX_DET; p += 256) {
        boxes_out[p * 4 + 0] = 0.f;
        boxes_out[p * 4 + 1] = 0.f;
        boxes_out[p * 4 + 2] = 0.f;
        boxes_out[p * 4 + 3] = 0.f;
        scores_out[p]  = 0.f;
        classes_out[p] = 0.f;
    }
    if (tid == 0) *numdet_out = (float)nd;
}

// ====================================================================
// Fallback (round-0 monolithic, validated) if ws is too small.
// ====================================================================
__global__ __launch_bounds__(1024) void nms_fallback(const float* __restrict__ pred,
                                                     float* __restrict__ out, int B) {
    const int b = blockIdx.x, tid = threadIdx.x;
    __shared__ u64 keys[NB];
    __shared__ float bx1[NB], by1[NB], bx2[NB], by2[NB];
    __shared__ int kc[NB];
    __shared__ int cnt[NCLASSES];
    __shared__ int overflow;
    const float* P = pred + (size_t)b * NB * 6;
    for (int i = tid; i < NB; i += 1024) {
        float s = P[i * 6 + 5];
        keys[i] = (s > CONF_T) ? (((u64)__float_as_uint(s) << 32) | (uint32_t)i)
                               : (u64)(uint32_t)i;
    }
    __syncthreads();
    for (int k = 2; k <= NB; k <<= 1)
        for (int j = k >> 1; j > 0; j >>= 1) {
            for (int i = tid; i < NB; i += 1024) {
                int ixj = i ^ j;
                if (ixj > i) {
                    u64 a = keys[i], c = keys[ixj];
                    bool up = ((i & k) == 0);
                    if (up ? (a < c) : (a > c)) { keys[i] = c; keys[ixj] = a; }
                }
            }
            __syncthreads();
        }
    for (int i = tid; i < NB; i += 1024) {
        u64 k = keys[i];
        int orig = (int)(uint32_t)k;
        const float* q = P + orig * 6;
        bx1[i] = q[0]; by1[i] = q[1]; bx2[i] = q[2]; by2[i] = q[3];
        kc[i] = ((k >> 32) != 0) ? (int)q[4] : -1;
    }
    __syncthreads();
    bool dirty = false;
    for (int i = 0; i < NB - 1; ++i) {
        if (i == 0 || dirty) { __syncthreads(); dirty = false; }
        int ci = kc[i];
        if (ci < 0) continue;
        dirty = true;
        float x1i = bx1[i], y1i = by1[i], x2i = bx2[i], y2i = by2[i];
        float ai = fmaxf(x2i - x1i, 0.f) * fmaxf(y2i - y1i, 0.f);
        for (int j = i + 1 + tid; j < NB; j += 1024) {
            if (kc[j] != ci) continue;
            float ix1 = fmaxf(x1i, bx1[j]), iy1 = fmaxf(y1i, by1[j]);
            float ix2 = fminf(x2i, bx2[j]), iy2 = fminf(y2i, by2[j]);
            float inter = fmaxf(ix2 - ix1, 0.f) * fmaxf(iy2 - iy1, 0.f);
            float aj = fmaxf(bx2[j] - bx1[j], 0.f) * fmaxf(by2[j] - by1[j], 0.f);
            if (inter / fmaxf(ai + aj - inter, 1e-8f) > IOU_T) kc[j] = -1;
        }
    }
    __syncthreads();
    for (int i = tid; i < NCLASSES; i += 1024) cnt[i] = 0;
    if (tid == 0) overflow = 0;
    __syncthreads();
    for (int i = tid; i < NB; i += 1024) if (kc[i] >= 0) atomicAdd(&cnt[kc[i]], 1);
    __syncthreads();
    if (tid < NCLASSES && cnt[tid] > MAX_PER_CLASS) atomicOr(&overflow, 1);
    __syncthreads();
    if (overflow) {
        if (tid == 0) {
            for (int c = 0; c < NCLASSES; ++c) cnt[c] = 0;
            for (int i = 0; i < NB; ++i)
                if (kc[i] >= 0 && ++cnt[kc[i]] > MAX_PER_CLASS) kc[i] = -1;
        }
        __syncthreads();
    }
    if (tid < 64) {
        const int lane = tid;
        float* boxes_out   = out + (size_t)b * MAX_DET * 4;
        float* scores_out  = out + (size_t)B * MAX_DET * 4 + (size_t)b * MAX_DET;
        float* classes_out = out + (size_t)B * MAX_DET * 5 + (size_t)b * MAX_DET;
        float* numdet_out  = out + (size_t)B * MAX_DET * 6 + b;
        int running = 0;
        for (int chunk = 0; chunk < NB / 64; ++chunk) {
            int j = chunk * 64 + lane;
            int c = kc[j];
            bool k = (c >= 0);
            u64 m = __ballot(k);
            int pos = running + __popcll(m & ((1ull << lane) - 1ull));
            if (k && pos < MAX_DET) {
                boxes_out[pos * 4 + 0] = bx1[j];
                boxes_out[pos * 4 + 1] = by1[j];
                boxes_out[pos * 4 + 2] = bx2[j];
                boxes_out[pos * 4 + 3] = by2[j];
                scores_out[pos]  = __uint_as_float((uint32_t)(keys[j] >> 32));
                classes_out[pos] = (float)c;
            }
            running += __popcll(m);
        }
        int nd = running < MAX_DET ? running : MAX_DET;
        for (int p = nd + lane; p < MAX_DET; p += 64) {
            boxes_out[p * 4 + 0] = 0.f; boxes_out[p * 4 + 1] = 0.f;
            boxes_out[p * 4 + 2] = 0.f; boxes_out[p * 4 + 3] = 0.f;
            scores_out[p] = 0.f; classes_out[p] = 0.f;
        }
        if (lane == 0) *numdet_out = (float)nd;
    }
}

extern "C" void kernel_launch(void* const* d_in, const int* in_sizes, int n_in,
                              void* d_out, int out_size, void* d_ws, size_t ws_size,
                              hipStream_t stream) {
    const float* pred = (const float*)d_in[0];
    float* out = (float*)d_out;
    const int B = in_sizes[0] / (NB * 6);

    u32* supMaskG = (u32*)d_ws;                       // B * 64 u32 = 2048-bit/batch
    const size_t need = (size_t)B * 64 * sizeof(u32);

    if (ws_size < need) {
        nms_fallback<<<B, 1024, 0, stream>>>(pred, out, B);
        return;
    }

    hipMemsetAsync(supMaskG, 0, need, stream);
    k_nms<<<dim3(NCLASSES, B), 64, 0, stream>>>(pred, supMaskG);
    k_out<<<B, 256, 0, stream>>>(pred, supMaskG, out, B);
}